// Round 6
// baseline (385.075 us; speedup 1.0000x reference)
//
#include <hip/hip_runtime.h>
#include <hip/hip_fp16.h>

// Qwen3 attention block: B=2 S=2048 HID=1024 NH=16 NKV=8 HD=128, causal.
// R6: attn -> 256-thr blocks, q-tile 128 (4 waves x 32 q), K-tile 64.
//     K/V staging shared by 4 waves (halved per-wave), slim LDS padding
//     (stride = 2 banks, free 2-way) to keep 3 blocks/CU = 12 waves/CU.
//     512 all-resident blocks, complement-paired work. Math identical to
//     the verified R3/R5 attention (16x16x32 MFMA, Ps round-trip).

typedef _Float16 f16;
typedef __attribute__((ext_vector_type(8))) _Float16 f16x8;
typedef __attribute__((ext_vector_type(4))) _Float16 f16x4;
typedef __attribute__((ext_vector_type(4))) float f32x4;

__constant__ const float kEps = 1e-6f;
// 1/sqrt(128) * log2(e): Q pre-scaled so attn softmax runs in exp2 domain
__constant__ const float kScaleL2 = 0.1275179120685481f;

// async global->LDS, 16B/lane; lds ptr must be wave-uniform (HW adds lane*16)
#define ASYNC_LD16(gp, lp)                                              \
  __builtin_amdgcn_global_load_lds(                                     \
      (const __attribute__((address_space(1))) void*)(gp),              \
      (__attribute__((address_space(3))) void*)(uint32_t)(uintptr_t)(lp), 16, 0, 0)

// max/sum reduce across the 16 lanes of a DPP row (our cl group)
__device__ __forceinline__ float dpp_max16(float v) {
  int x;
  x = __builtin_amdgcn_update_dpp(0, __builtin_bit_cast(int, v), 0xB1, 0xF, 0xF, true);
  v = fmaxf(v, __builtin_bit_cast(float, x));
  x = __builtin_amdgcn_update_dpp(0, __builtin_bit_cast(int, v), 0x4E, 0xF, 0xF, true);
  v = fmaxf(v, __builtin_bit_cast(float, x));
  x = __builtin_amdgcn_update_dpp(0, __builtin_bit_cast(int, v), 0x141, 0xF, 0xF, true);
  v = fmaxf(v, __builtin_bit_cast(float, x));
  x = __builtin_amdgcn_update_dpp(0, __builtin_bit_cast(int, v), 0x140, 0xF, 0xF, true);
  v = fmaxf(v, __builtin_bit_cast(float, x));
  return v;
}
__device__ __forceinline__ float dpp_sum16(float v) {
  int x;
  x = __builtin_amdgcn_update_dpp(0, __builtin_bit_cast(int, v), 0xB1, 0xF, 0xF, true);
  v += __builtin_bit_cast(float, x);
  x = __builtin_amdgcn_update_dpp(0, __builtin_bit_cast(int, v), 0x4E, 0xF, 0xF, true);
  v += __builtin_bit_cast(float, x);
  x = __builtin_amdgcn_update_dpp(0, __builtin_bit_cast(int, v), 0x141, 0xF, 0xF, true);
  v += __builtin_bit_cast(float, x);
  x = __builtin_amdgcn_update_dpp(0, __builtin_bit_cast(int, v), 0x140, 0xF, 0xF, true);
  v += __builtin_bit_cast(float, x);
  return v;
}

// ------------------------------------------------ fused cast f32->f16 (all 5)
__global__ __launch_bounds__(256) void cast_all(
    const float* __restrict__ h, const float* __restrict__ wq,
    const float* __restrict__ wk, const float* __restrict__ wv,
    const float* __restrict__ wo, f16* __restrict__ hb,
    f16* __restrict__ wqkv, f16* __restrict__ wob) {
  const int idx = blockIdx.x * 256 + threadIdx.x;
  const float* src;
  f16* dst;
  int base;
  if (idx < 1048576) { src = h;  dst = hb;                  base = 0; }
  else if (idx < 1572864) { src = wq; dst = wqkv;               base = 1048576; }
  else if (idx < 1835008) { src = wk; dst = wqkv + 2048 * 1024; base = 1572864; }
  else if (idx < 2097152) { src = wv; dst = wqkv + 3072 * 1024; base = 1835008; }
  else { src = wo; dst = wob; base = 2097152; }
  const int i = (idx - base) * 4;
  f32x4 v = *reinterpret_cast<const f32x4*>(src + i);
  f16x4 o;
  o.x = (f16)v.x; o.y = (f16)v.y; o.z = (f16)v.z; o.w = (f16)v.w;
  *reinterpret_cast<f16x4*>(dst + i) = o;
}

// --------------------------- C[M,N] = A[M,K]*B[N,K]^T, f16 out (QKV proj)
__global__ __launch_bounds__(256) void gemm_bt_h(const f16* __restrict__ A,
                                                 const f16* __restrict__ Bm,
                                                 f16* __restrict__ C,
                                                 int M, int N, int K) {
  __shared__ __align__(16) f16 As[128][64];
  __shared__ __align__(16) f16 Bs[128][64];
  const int tid = threadIdx.x;
  const int lane = tid & 63;
  const int wave = tid >> 6;
  const int cl = lane & 15;
  const int quad = lane >> 4;
  const int wm = (wave >> 1) * 64;
  const int wn = (wave & 1) * 64;
  const int tm = blockIdx.y * 128;
  const int tn = blockIdx.x * 128;
  const int r0 = tid >> 3;
  const int csw = ((tid & 7) ^ (r0 & 7)) * 8;

  const f16* Ab = A + (size_t)(tm + r0) * K + csw;
  const f16* Bb = Bm + (size_t)(tn + r0) * K + csw;
  char* Al = (char*)As + wave * 1024;
  char* Bl = (char*)Bs + wave * 1024;

  f32x4 acc[4][4] = {};

  for (int k0 = 0; k0 < K; k0 += 64) {
#pragma unroll
    for (int c = 0; c < 4; ++c) {
      ASYNC_LD16(Ab + (size_t)(c * 32) * K + k0, Al + c * 4096);
      ASYNC_LD16(Bb + (size_t)(c * 32) * K + k0, Bl + c * 4096);
    }
    __syncthreads();
#pragma unroll
    for (int kk = 0; kk < 2; ++kk) {
      f16x8 af[4], bf[4];
#pragma unroll
      for (int mi = 0; mi < 4; ++mi)
        af[mi] = *reinterpret_cast<const f16x8*>(
            &As[wm + mi * 16 + cl][((kk * 4 + quad) ^ (cl & 7)) * 8]);
#pragma unroll
      for (int ni = 0; ni < 4; ++ni)
        bf[ni] = *reinterpret_cast<const f16x8*>(
            &Bs[wn + ni * 16 + cl][((kk * 4 + quad) ^ (cl & 7)) * 8]);
#pragma unroll
      for (int mi = 0; mi < 4; ++mi)
#pragma unroll
        for (int ni = 0; ni < 4; ++ni)
          acc[mi][ni] =
              __builtin_amdgcn_mfma_f32_16x16x32_f16(af[mi], bf[ni], acc[mi][ni], 0, 0, 0);
    }
    __syncthreads();
  }
#pragma unroll
  for (int mi = 0; mi < 4; ++mi)
#pragma unroll
    for (int ni = 0; ni < 4; ++ni)
#pragma unroll
      for (int r = 0; r < 4; ++r)
        C[(size_t)(tm + wm + mi * 16 + quad * 4 + r) * N + tn + wn + ni * 16 + cl] =
            (f16)acc[mi][ni][r];
}

// --------------------------- C[M,N] = A[M,K]*B[N,K]^T, f32 out (out proj)
// 64x128 tile (512 blocks for M=4096,N=1024 -> 2 blocks/CU), BK=64.
__global__ __launch_bounds__(256) void gemm_bt64(const f16* __restrict__ A,
                                                 const f16* __restrict__ Bm,
                                                 float* __restrict__ C,
                                                 int M, int N, int K) {
  __shared__ __align__(16) f16 As[64][64];
  __shared__ __align__(16) f16 Bs[128][64];
  const int tid = threadIdx.x;
  const int lane = tid & 63;
  const int wave = tid >> 6;
  const int cl = lane & 15;
  const int quad = lane >> 4;
  const int wm = (wave >> 1) * 32;
  const int wn = (wave & 1) * 64;
  const int tm = blockIdx.y * 64;
  const int tn = blockIdx.x * 128;
  const int r0 = tid >> 3;
  const int csw = ((tid & 7) ^ (r0 & 7)) * 8;

  const f16* Ab = A + (size_t)(tm + r0) * K + csw;
  const f16* Bb = Bm + (size_t)(tn + r0) * K + csw;
  char* Al = (char*)As + wave * 1024;
  char* Bl = (char*)Bs + wave * 1024;

  f32x4 acc[2][4] = {};

  for (int k0 = 0; k0 < K; k0 += 64) {
#pragma unroll
    for (int c = 0; c < 2; ++c)
      ASYNC_LD16(Ab + (size_t)(c * 32) * K + k0, Al + c * 4096);
#pragma unroll
    for (int c = 0; c < 4; ++c)
      ASYNC_LD16(Bb + (size_t)(c * 32) * K + k0, Bl + c * 4096);
    __syncthreads();
#pragma unroll
    for (int kk = 0; kk < 2; ++kk) {
      f16x8 af[2], bf[4];
#pragma unroll
      for (int mi = 0; mi < 2; ++mi)
        af[mi] = *reinterpret_cast<const f16x8*>(
            &As[wm + mi * 16 + cl][((kk * 4 + quad) ^ (cl & 7)) * 8]);
#pragma unroll
      for (int ni = 0; ni < 4; ++ni)
        bf[ni] = *reinterpret_cast<const f16x8*>(
            &Bs[wn + ni * 16 + cl][((kk * 4 + quad) ^ (cl & 7)) * 8]);
#pragma unroll
      for (int mi = 0; mi < 2; ++mi)
#pragma unroll
        for (int ni = 0; ni < 4; ++ni)
          acc[mi][ni] =
              __builtin_amdgcn_mfma_f32_16x16x32_f16(af[mi], bf[ni], acc[mi][ni], 0, 0, 0);
    }
    __syncthreads();
  }
#pragma unroll
  for (int mi = 0; mi < 2; ++mi)
#pragma unroll
    for (int ni = 0; ni < 4; ++ni)
#pragma unroll
      for (int r = 0; r < 4; ++r)
        C[(size_t)(tm + wm + mi * 16 + quad * 4 + r) * N + tn + wn + ni * 16 + cl] =
            acc[mi][ni][r];
}

// -------------------------- RMSNorm + RoPE + transpose for Q,K (wave per row)
__global__ __launch_bounds__(256) void rope_norm(
    const f16* __restrict__ qkvh,
    const float* __restrict__ cosT, const float* __restrict__ sinT,
    const float* __restrict__ qw, const float* __restrict__ kw,
    f16* __restrict__ qt, f16* __restrict__ kt) {
  const int gw = blockIdx.x * 4 + (threadIdx.x >> 6);
  const int lane = threadIdx.x & 63;
  const int head = gw % 24;
  const int bs = gw / 24;
  const bool isq = head < 16;
  const f16* src = qkvh + (size_t)bs * 4096 +
                   (isq ? head * 128 : 2048 + (head - 16) * 128);
  const float x1 = (float)src[lane];
  const float x2 = (float)src[lane + 64];
  float ss = x1 * x1 + x2 * x2;
#pragma unroll
  for (int off = 32; off >= 1; off >>= 1) ss += __shfl_xor(ss, off);
  const float rms = rsqrtf(ss * (1.0f / 128.0f) + kEps);
  const float* w = isq ? qw : kw;
  const float n1 = x1 * rms * w[lane];
  const float n2 = x2 * rms * w[lane + 64];
  const float* cb = cosT + (size_t)bs * 128;
  const float* sb = sinT + (size_t)bs * 128;
  const float o1 = n1 * cb[lane] - n2 * sb[lane];
  const float o2 = n2 * cb[lane + 64] + n1 * sb[lane + 64];
  const int b = bs >> 11;
  const int s = bs & 2047;
  f16* dst;
  float sc;
  if (isq) {
    dst = qt + ((size_t)(b * 16 + head) * 2048 + s) * 128;
    sc = kScaleL2;
  } else {
    dst = kt + ((size_t)(b * 8 + (head - 16)) * 2048 + s) * 128;
    sc = 1.0f;
  }
  dst[lane] = (f16)(o1 * sc);
  dst[lane + 64] = (f16)(o2 * sc);
}

// ------------------------------- V slice of qkvh f16 -> (B*NKV, HD, S) f16
__global__ __launch_bounds__(256) void v_transpose(const f16* __restrict__ qkvh,
                                                   f16* __restrict__ vt) {
  __shared__ __align__(16) f16 tile[64][136];
  const int bh = blockIdx.y;
  const int b = bh >> 3, h = bh & 7;
  const int s0 = blockIdx.x * 64;
  const int tid = threadIdx.x;
#pragma unroll
  for (int i = 0; i < 4; ++i) {
    int c = tid + i * 256;
    int s = c >> 4;
    int cg = c & 15;
    f16x8 v = *reinterpret_cast<const f16x8*>(
        qkvh + (size_t)(b * 2048 + s0 + s) * 4096 + 3072 + h * 128 + cg * 8);
    *reinterpret_cast<f16x8*>(&tile[s][cg * 8]) = v;
  }
  __syncthreads();
#pragma unroll
  for (int i = 0; i < 4; ++i) {
    int c = tid + i * 256;
    int d = c >> 3;
    int sB = (c & 7) * 8;
    f16x8 o;
#pragma unroll
    for (int j = 0; j < 8; ++j) o[j] = tile[sB + j][d];
    *reinterpret_cast<f16x8*>(vt + ((size_t)(b * 8 + h) * 128 + d) * 2048 + s0 + sB) = o;
  }
}

// ------------------------------------------------------- flash attention (causal)
// 512 blocks x 256 threads (4 waves). q-tile 128; wave wv owns q-rows
// [q0+wv*32, +32). K-tile 64 staged once per block (shared by 4 waves).
// Slim padding: strides 132/68 f16 (= 2 banks mod 32; 2-way aliasing free).
// Grid: bid<256 -> t=15-(bid>>5)&7... complement pairing so CU pairs
// (bid, bid+256) total 34 iters. bh = bid&31 keeps heads XCD-grouped.
__global__ __launch_bounds__(256) void attn(const f16* __restrict__ Qt,
                                            const f16* __restrict__ Kt,
                                            const f16* __restrict__ Vt,
                                            f16* __restrict__ Ot) {
  __shared__ __align__(16) f16 Ks[64][132];   // 16.9 KB
  __shared__ __align__(16) f16 Vs[128][68];   // 17.4 KB
  __shared__ __align__(16) f16 Ps[4][32][68]; // 17.4 KB  (total ~50.5 KB)

  const int bid = blockIdx.x;
  const int bh = bid & 31;
  const int g = (bid >> 5) & 7;
  const int t = (bid < 256) ? (15 - g) : g;   // complement pairing
  const int q0 = t * 128;
  const int b = bh >> 4, h = bh & 15;
  const int kv = h >> 1;

  const int tid = threadIdx.x;
  const int lane = tid & 63, wv = tid >> 6;
  const int cl = lane & 15, quad = lane >> 4;
  const int qw0 = q0 + wv * 32;               // wave's first q-row

  const f16* qbase = Qt + ((size_t)(b * 16 + h) * 2048 + qw0 + cl) * 128;
  f16x8 aq[2][4];
#pragma unroll
  for (int mi = 0; mi < 2; ++mi)
#pragma unroll
    for (int kk = 0; kk < 4; ++kk)
      aq[mi][kk] =
          *reinterpret_cast<const f16x8*>(qbase + mi * 16 * 128 + kk * 32 + quad * 8);

  const f16* kbase = Kt + (size_t)(b * 8 + kv) * 2048 * 128;
  const f16* vbase = Vt + (size_t)(b * 8 + kv) * 128 * 2048;

  float m_[2][4], l_[2][4];
#pragma unroll
  for (int mi = 0; mi < 2; ++mi)
#pragma unroll
    for (int r = 0; r < 4; ++r) { m_[mi][r] = -1e30f; l_[mi][r] = 0.f; }
  f32x4 oacc[2][8] = {};

  const int nIter = 2 * t + 2;
  for (int it = 0; it < nIter; ++it) {
    const int kt0 = it * 64;
    // ---- stage K (64x128) + V^T (128x64): 1024+1024 16B chunks, 256 thr
#pragma unroll
    for (int i = 0; i < 4; ++i) {
      int c = tid + i * 256;
      int krow = c >> 4, d0 = (c & 15) * 8;
      *reinterpret_cast<int4*>(&Ks[krow][d0]) =
          *reinterpret_cast<const int4*>(kbase + (size_t)(kt0 + krow) * 128 + d0);
      int dr = c >> 3, ko = (c & 7) * 8;
      *reinterpret_cast<int4*>(&Vs[dr][ko]) =
          *reinterpret_cast<const int4*>(vbase + (size_t)dr * 2048 + kt0 + ko);
    }
    __syncthreads();
    if (kt0 <= qw0 + 31) {  // skip fully-masked tiles (lower waves, last iter)
      f32x4 sacc[2][4] = {};
#pragma unroll
      for (int kk = 0; kk < 4; ++kk)
#pragma unroll
        for (int ni = 0; ni < 4; ++ni) {
          f16x8 bk = *reinterpret_cast<const f16x8*>(&Ks[ni * 16 + cl][kk * 32 + quad * 8]);
#pragma unroll
          for (int mi = 0; mi < 2; ++mi)
            sacc[mi][ni] =
                __builtin_amdgcn_mfma_f32_16x16x32_f16(aq[mi][kk], bk, sacc[mi][ni], 0, 0, 0);
        }
      if (kt0 + 63 > qw0) {  // diagonal region for this wave
#pragma unroll
        for (int mi = 0; mi < 2; ++mi) {
          const int qr = qw0 + mi * 16 + quad * 4;
#pragma unroll
          for (int ni = 0; ni < 4; ++ni) {
            const int kg = kt0 + ni * 16 + cl;
#pragma unroll
            for (int r = 0; r < 4; ++r)
              if (kg > qr + r) sacc[mi][ni][r] = -1e30f;
          }
        }
      }
      float alv[2][4];
#pragma unroll
      for (int mi = 0; mi < 2; ++mi)
#pragma unroll
        for (int r = 0; r < 4; ++r) {
          float mx = fmaxf(fmaxf(sacc[mi][0][r], sacc[mi][1][r]),
                           fmaxf(sacc[mi][2][r], sacc[mi][3][r]));
          mx = dpp_max16(mx);
          const float nm = fmaxf(m_[mi][r], mx);
          const float al = __builtin_amdgcn_exp2f(m_[mi][r] - nm);
          m_[mi][r] = nm;
          float ps = 0.f;
#pragma unroll
          for (int ni = 0; ni < 4; ++ni) {
            const float p = __builtin_amdgcn_exp2f(sacc[mi][ni][r] - nm);
            sacc[mi][ni][r] = p;
            ps += p;
          }
          l_[mi][r] = l_[mi][r] * al + ps;
          alv[mi][r] = al;
        }
#pragma unroll
      for (int mi = 0; mi < 2; ++mi)
#pragma unroll
        for (int ni = 0; ni < 4; ++ni)
#pragma unroll
          for (int r = 0; r < 4; ++r)
            Ps[wv][mi * 16 + quad * 4 + r][ni * 16 + cl] = (f16)sacc[mi][ni][r];
#pragma unroll
      for (int mi = 0; mi < 2; ++mi)
#pragma unroll
        for (int dg = 0; dg < 8; ++dg)
#pragma unroll
          for (int r = 0; r < 4; ++r) oacc[mi][dg][r] *= alv[mi][r];
      asm volatile("s_waitcnt lgkmcnt(0)" ::: "memory");  // Ps is per-wave
      f16x8 ap[2][2];
#pragma unroll
      for (int mi = 0; mi < 2; ++mi)
#pragma unroll
        for (int kh = 0; kh < 2; ++kh)
          ap[mi][kh] =
              *reinterpret_cast<const f16x8*>(&Ps[wv][mi * 16 + cl][kh * 32 + quad * 8]);
#pragma unroll
      for (int kh = 0; kh < 2; ++kh)
#pragma unroll
        for (int dg = 0; dg < 8; ++dg) {
          f16x8 bv = *reinterpret_cast<const f16x8*>(&Vs[dg * 16 + cl][kh * 32 + quad * 8]);
#pragma unroll
          for (int mi = 0; mi < 2; ++mi)
            oacc[mi][dg] =
                __builtin_amdgcn_mfma_f32_16x16x32_f16(ap[mi][kh], bv, oacc[mi][dg], 0, 0, 0);
        }
    }
    __syncthreads();
  }
#pragma unroll
  for (int mi = 0; mi < 2; ++mi)
#pragma unroll
    for (int r = 0; r < 4; ++r) {
      const float inv = 1.0f / dpp_sum16(l_[mi][r]);
      const int qg = qw0 + mi * 16 + quad * 4 + r;
#pragma unroll
      for (int dg = 0; dg < 8; ++dg)
        Ot[(size_t)(b * 2048 + qg) * 2048 + h * 128 + dg * 16 + cl] =
            (f16)(oacc[mi][dg][r] * inv);
    }
}

// ---------------------------------------------------------------------- launch
extern "C" void kernel_launch(void* const* d_in, const int* in_sizes, int n_in,
                              void* d_out, int out_size, void* d_ws, size_t ws_size,
                              hipStream_t stream) {
  (void)in_sizes; (void)n_in; (void)out_size; (void)ws_size;
  const float* hidden = (const float*)d_in[0];
  const float* cosT = (const float*)d_in[1];
  const float* sinT = (const float*)d_in[2];
  // d_in[3] = attention_mask: exactly causal triu * -1e9 -> computed analytically
  const float* Wq = (const float*)d_in[4];
  const float* Wk = (const float*)d_in[5];
  const float* Wv = (const float*)d_in[6];
  const float* Wo = (const float*)d_in[7];
  const float* qnw = (const float*)d_in[8];
  const float* knw = (const float*)d_in[9];
  float* out = (float*)d_out;

  char* ws = (char*)d_ws;
  size_t off = 0;
  auto alloc = [&](size_t bytes) {
    char* p = ws + off;
    off += (bytes + 255) & ~(size_t)255;
    return p;
  };
  f16* hb = (f16*)alloc(4096ull * 1024 * 2);
  f16* wqkv = (f16*)alloc(4096ull * 1024 * 2);   // [Wq;Wk;Wv] rows
  f16* wob = (f16*)alloc(1024ull * 2048 * 2);
  f16* qkvh = (f16*)alloc(4096ull * 4096 * 2);
  f16* qt = (f16*)alloc(32ull * 2048 * 128 * 2);
  f16* kt = (f16*)alloc(16ull * 2048 * 128 * 2);
  f16* vt = (f16*)alloc(16ull * 2048 * 128 * 2);
  f16* ot = (f16*)alloc(4096ull * 2048 * 2);

  cast_all<<<10240, 256, 0, stream>>>(hidden, Wq, Wk, Wv, Wo, hb, wqkv, wob);

  gemm_bt_h<<<dim3(32, 32), 256, 0, stream>>>(hb, wqkv, qkvh, 4096, 4096, 1024);

  rope_norm<<<24576, 256, 0, stream>>>(qkvh, cosT, sinT, qnw, knw, qt, kt);
  v_transpose<<<dim3(32, 16), 256, 0, stream>>>(qkvh, vt);

  attn<<<512, 256, 0, stream>>>(qt, kt, vt, ot);

  gemm_bt64<<<dim3(8, 64), 256, 0, stream>>>(ot, wob, out, 4096, 1024, 2048);
}

// Round 7
// 336.573 us; speedup vs baseline: 1.1441x; 1.1441x over previous
//
#include <hip/hip_runtime.h>
#include <hip/hip_fp16.h>

// Qwen3 attention block: B=2 S=2048 HID=1024 NH=16 NKV=8 HD=128, causal.
// R7: R6 structure (256-thr, 4 waves x 32 q, K-tile 64 staged once per
//     block, complement-paired 512-block grid) with the R6 regression
//     fixed: ALL LDS row strides are multiples of 16 B (R6's 264/136 B
//     strides broke b128 alignment -> split DS ops, 2x slowdown).
//     K/V staged via global_load_lds with XOR swizzle (R4-verified
//     pattern): unpadded tiles, conflict-free aligned fragment reads.

typedef _Float16 f16;
typedef __attribute__((ext_vector_type(8))) _Float16 f16x8;
typedef __attribute__((ext_vector_type(4))) _Float16 f16x4;
typedef __attribute__((ext_vector_type(4))) float f32x4;

__constant__ const float kEps = 1e-6f;
// 1/sqrt(128) * log2(e): Q pre-scaled so attn softmax runs in exp2 domain
__constant__ const float kScaleL2 = 0.1275179120685481f;

// async global->LDS, 16B/lane; lds ptr must be wave-uniform (HW adds lane*16)
#define ASYNC_LD16(gp, lp)                                              \
  __builtin_amdgcn_global_load_lds(                                     \
      (const __attribute__((address_space(1))) void*)(gp),              \
      (__attribute__((address_space(3))) void*)(uint32_t)(uintptr_t)(lp), 16, 0, 0)

// max/sum reduce across the 16 lanes of a DPP row (our cl group)
__device__ __forceinline__ float dpp_max16(float v) {
  int x;
  x = __builtin_amdgcn_update_dpp(0, __builtin_bit_cast(int, v), 0xB1, 0xF, 0xF, true);
  v = fmaxf(v, __builtin_bit_cast(float, x));
  x = __builtin_amdgcn_update_dpp(0, __builtin_bit_cast(int, v), 0x4E, 0xF, 0xF, true);
  v = fmaxf(v, __builtin_bit_cast(float, x));
  x = __builtin_amdgcn_update_dpp(0, __builtin_bit_cast(int, v), 0x141, 0xF, 0xF, true);
  v = fmaxf(v, __builtin_bit_cast(float, x));
  x = __builtin_amdgcn_update_dpp(0, __builtin_bit_cast(int, v), 0x140, 0xF, 0xF, true);
  v = fmaxf(v, __builtin_bit_cast(float, x));
  return v;
}
__device__ __forceinline__ float dpp_sum16(float v) {
  int x;
  x = __builtin_amdgcn_update_dpp(0, __builtin_bit_cast(int, v), 0xB1, 0xF, 0xF, true);
  v += __builtin_bit_cast(float, x);
  x = __builtin_amdgcn_update_dpp(0, __builtin_bit_cast(int, v), 0x4E, 0xF, 0xF, true);
  v += __builtin_bit_cast(float, x);
  x = __builtin_amdgcn_update_dpp(0, __builtin_bit_cast(int, v), 0x141, 0xF, 0xF, true);
  v += __builtin_bit_cast(float, x);
  x = __builtin_amdgcn_update_dpp(0, __builtin_bit_cast(int, v), 0x140, 0xF, 0xF, true);
  v += __builtin_bit_cast(float, x);
  return v;
}

// ------------------------------------------------ fused cast f32->f16 (all 5)
__global__ __launch_bounds__(256) void cast_all(
    const float* __restrict__ h, const float* __restrict__ wq,
    const float* __restrict__ wk, const float* __restrict__ wv,
    const float* __restrict__ wo, f16* __restrict__ hb,
    f16* __restrict__ wqkv, f16* __restrict__ wob) {
  const int idx = blockIdx.x * 256 + threadIdx.x;
  const float* src;
  f16* dst;
  int base;
  if (idx < 1048576) { src = h;  dst = hb;                  base = 0; }
  else if (idx < 1572864) { src = wq; dst = wqkv;               base = 1048576; }
  else if (idx < 1835008) { src = wk; dst = wqkv + 2048 * 1024; base = 1572864; }
  else if (idx < 2097152) { src = wv; dst = wqkv + 3072 * 1024; base = 1835008; }
  else { src = wo; dst = wob; base = 2097152; }
  const int i = (idx - base) * 4;
  f32x4 v = *reinterpret_cast<const f32x4*>(src + i);
  f16x4 o;
  o.x = (f16)v.x; o.y = (f16)v.y; o.z = (f16)v.z; o.w = (f16)v.w;
  *reinterpret_cast<f16x4*>(dst + i) = o;
}

// --------------------------- C[M,N] = A[M,K]*B[N,K]^T, f16 out (QKV proj)
__global__ __launch_bounds__(256) void gemm_bt_h(const f16* __restrict__ A,
                                                 const f16* __restrict__ Bm,
                                                 f16* __restrict__ C,
                                                 int M, int N, int K) {
  __shared__ __align__(16) f16 As[128][64];
  __shared__ __align__(16) f16 Bs[128][64];
  const int tid = threadIdx.x;
  const int lane = tid & 63;
  const int wave = tid >> 6;
  const int cl = lane & 15;
  const int quad = lane >> 4;
  const int wm = (wave >> 1) * 64;
  const int wn = (wave & 1) * 64;
  const int tm = blockIdx.y * 128;
  const int tn = blockIdx.x * 128;
  const int r0 = tid >> 3;
  const int csw = ((tid & 7) ^ (r0 & 7)) * 8;

  const f16* Ab = A + (size_t)(tm + r0) * K + csw;
  const f16* Bb = Bm + (size_t)(tn + r0) * K + csw;
  char* Al = (char*)As + wave * 1024;
  char* Bl = (char*)Bs + wave * 1024;

  f32x4 acc[4][4] = {};

  for (int k0 = 0; k0 < K; k0 += 64) {
#pragma unroll
    for (int c = 0; c < 4; ++c) {
      ASYNC_LD16(Ab + (size_t)(c * 32) * K + k0, Al + c * 4096);
      ASYNC_LD16(Bb + (size_t)(c * 32) * K + k0, Bl + c * 4096);
    }
    __syncthreads();
#pragma unroll
    for (int kk = 0; kk < 2; ++kk) {
      f16x8 af[4], bf[4];
#pragma unroll
      for (int mi = 0; mi < 4; ++mi)
        af[mi] = *reinterpret_cast<const f16x8*>(
            &As[wm + mi * 16 + cl][((kk * 4 + quad) ^ (cl & 7)) * 8]);
#pragma unroll
      for (int ni = 0; ni < 4; ++ni)
        bf[ni] = *reinterpret_cast<const f16x8*>(
            &Bs[wn + ni * 16 + cl][((kk * 4 + quad) ^ (cl & 7)) * 8]);
#pragma unroll
      for (int mi = 0; mi < 4; ++mi)
#pragma unroll
        for (int ni = 0; ni < 4; ++ni)
          acc[mi][ni] =
              __builtin_amdgcn_mfma_f32_16x16x32_f16(af[mi], bf[ni], acc[mi][ni], 0, 0, 0);
    }
    __syncthreads();
  }
#pragma unroll
  for (int mi = 0; mi < 4; ++mi)
#pragma unroll
    for (int ni = 0; ni < 4; ++ni)
#pragma unroll
      for (int r = 0; r < 4; ++r)
        C[(size_t)(tm + wm + mi * 16 + quad * 4 + r) * N + tn + wn + ni * 16 + cl] =
            (f16)acc[mi][ni][r];
}

// --------------------------- C[M,N] = A[M,K]*B[N,K]^T, f32 out (out proj)
__global__ __launch_bounds__(256) void gemm_bt64(const f16* __restrict__ A,
                                                 const f16* __restrict__ Bm,
                                                 float* __restrict__ C,
                                                 int M, int N, int K) {
  __shared__ __align__(16) f16 As[64][64];
  __shared__ __align__(16) f16 Bs[128][64];
  const int tid = threadIdx.x;
  const int lane = tid & 63;
  const int wave = tid >> 6;
  const int cl = lane & 15;
  const int quad = lane >> 4;
  const int wm = (wave >> 1) * 32;
  const int wn = (wave & 1) * 64;
  const int tm = blockIdx.y * 64;
  const int tn = blockIdx.x * 128;
  const int r0 = tid >> 3;
  const int csw = ((tid & 7) ^ (r0 & 7)) * 8;

  const f16* Ab = A + (size_t)(tm + r0) * K + csw;
  const f16* Bb = Bm + (size_t)(tn + r0) * K + csw;
  char* Al = (char*)As + wave * 1024;
  char* Bl = (char*)Bs + wave * 1024;

  f32x4 acc[2][4] = {};

  for (int k0 = 0; k0 < K; k0 += 64) {
#pragma unroll
    for (int c = 0; c < 2; ++c)
      ASYNC_LD16(Ab + (size_t)(c * 32) * K + k0, Al + c * 4096);
#pragma unroll
    for (int c = 0; c < 4; ++c)
      ASYNC_LD16(Bb + (size_t)(c * 32) * K + k0, Bl + c * 4096);
    __syncthreads();
#pragma unroll
    for (int kk = 0; kk < 2; ++kk) {
      f16x8 af[2], bf[4];
#pragma unroll
      for (int mi = 0; mi < 2; ++mi)
        af[mi] = *reinterpret_cast<const f16x8*>(
            &As[wm + mi * 16 + cl][((kk * 4 + quad) ^ (cl & 7)) * 8]);
#pragma unroll
      for (int ni = 0; ni < 4; ++ni)
        bf[ni] = *reinterpret_cast<const f16x8*>(
            &Bs[wn + ni * 16 + cl][((kk * 4 + quad) ^ (cl & 7)) * 8]);
#pragma unroll
      for (int mi = 0; mi < 2; ++mi)
#pragma unroll
        for (int ni = 0; ni < 4; ++ni)
          acc[mi][ni] =
              __builtin_amdgcn_mfma_f32_16x16x32_f16(af[mi], bf[ni], acc[mi][ni], 0, 0, 0);
    }
    __syncthreads();
  }
#pragma unroll
  for (int mi = 0; mi < 2; ++mi)
#pragma unroll
    for (int ni = 0; ni < 4; ++ni)
#pragma unroll
      for (int r = 0; r < 4; ++r)
        C[(size_t)(tm + wm + mi * 16 + quad * 4 + r) * N + tn + wn + ni * 16 + cl] =
            acc[mi][ni][r];
}

// -------------------------- RMSNorm + RoPE + transpose for Q,K (wave per row)
__global__ __launch_bounds__(256) void rope_norm(
    const f16* __restrict__ qkvh,
    const float* __restrict__ cosT, const float* __restrict__ sinT,
    const float* __restrict__ qw, const float* __restrict__ kw,
    f16* __restrict__ qt, f16* __restrict__ kt) {
  const int gw = blockIdx.x * 4 + (threadIdx.x >> 6);
  const int lane = threadIdx.x & 63;
  const int head = gw % 24;
  const int bs = gw / 24;
  const bool isq = head < 16;
  const f16* src = qkvh + (size_t)bs * 4096 +
                   (isq ? head * 128 : 2048 + (head - 16) * 128);
  const float x1 = (float)src[lane];
  const float x2 = (float)src[lane + 64];
  float ss = x1 * x1 + x2 * x2;
#pragma unroll
  for (int off = 32; off >= 1; off >>= 1) ss += __shfl_xor(ss, off);
  const float rms = rsqrtf(ss * (1.0f / 128.0f) + kEps);
  const float* w = isq ? qw : kw;
  const float n1 = x1 * rms * w[lane];
  const float n2 = x2 * rms * w[lane + 64];
  const float* cb = cosT + (size_t)bs * 128;
  const float* sb = sinT + (size_t)bs * 128;
  const float o1 = n1 * cb[lane] - n2 * sb[lane];
  const float o2 = n2 * cb[lane + 64] + n1 * sb[lane + 64];
  const int b = bs >> 11;
  const int s = bs & 2047;
  f16* dst;
  float sc;
  if (isq) {
    dst = qt + ((size_t)(b * 16 + head) * 2048 + s) * 128;
    sc = kScaleL2;
  } else {
    dst = kt + ((size_t)(b * 8 + (head - 16)) * 2048 + s) * 128;
    sc = 1.0f;
  }
  dst[lane] = (f16)(o1 * sc);
  dst[lane + 64] = (f16)(o2 * sc);
}

// ------------------------------- V slice of qkvh f16 -> (B*NKV, HD, S) f16
__global__ __launch_bounds__(256) void v_transpose(const f16* __restrict__ qkvh,
                                                   f16* __restrict__ vt) {
  __shared__ __align__(16) f16 tile[64][136];
  const int bh = blockIdx.y;
  const int b = bh >> 3, h = bh & 7;
  const int s0 = blockIdx.x * 64;
  const int tid = threadIdx.x;
#pragma unroll
  for (int i = 0; i < 4; ++i) {
    int c = tid + i * 256;
    int s = c >> 4;
    int cg = c & 15;
    f16x8 v = *reinterpret_cast<const f16x8*>(
        qkvh + (size_t)(b * 2048 + s0 + s) * 4096 + 3072 + h * 128 + cg * 8);
    *reinterpret_cast<f16x8*>(&tile[s][cg * 8]) = v;
  }
  __syncthreads();
#pragma unroll
  for (int i = 0; i < 4; ++i) {
    int c = tid + i * 256;
    int d = c >> 3;
    int sB = (c & 7) * 8;
    f16x8 o;
#pragma unroll
    for (int j = 0; j < 8; ++j) o[j] = tile[sB + j][d];
    *reinterpret_cast<f16x8*>(vt + ((size_t)(b * 8 + h) * 128 + d) * 2048 + s0 + sB) = o;
  }
}

// ------------------------------------------------------- flash attention (causal)
// 512 blocks x 256 threads (4 waves). q-tile 128; wave wv owns q-rows
// [q0+wv*32, +32). K-tile 64 staged once per block via global_load_lds with
// XOR swizzle (unpadded tiles; stored col-group g' = g ^ (row&7); fragment
// reads undo it -> 16B-aligned b128, 2-way banks = free). Ps stride 72
// (144 B, 16B-aligned). Complement-paired grid: bid<256 -> t=15-g else g.
__global__ __launch_bounds__(256) void attn(const f16* __restrict__ Qt,
                                            const f16* __restrict__ Kt,
                                            const f16* __restrict__ Vt,
                                            f16* __restrict__ Ot) {
  __shared__ __align__(16) f16 Ks[64 * 128];   // 16 KB, swizzled (s,d)
  __shared__ __align__(16) f16 Vs[128 * 64];   // 16 KB, swizzled (d,s)
  __shared__ __align__(16) f16 Ps[4][32][72];  // 18 KB, per-wave P round-trip

  const int bid = blockIdx.x;
  const int bh = bid & 31;
  const int g = (bid >> 5) & 7;
  const int t = (bid < 256) ? (15 - g) : g;   // complement pairing
  const int q0 = t * 128;
  const int b = bh >> 4, h = bh & 15;
  const int kv = h >> 1;

  const int tid = threadIdx.x;
  const int lane = tid & 63, wv = tid >> 6;
  const int cl = lane & 15, quad = lane >> 4;
  const int qw0 = q0 + wv * 32;               // wave's first q-row

  const f16* qbase = Qt + ((size_t)(b * 16 + h) * 2048 + qw0 + cl) * 128;
  f16x8 aq[2][4];
#pragma unroll
  for (int mi = 0; mi < 2; ++mi)
#pragma unroll
    for (int kk = 0; kk < 4; ++kk)
      aq[mi][kk] =
          *reinterpret_cast<const f16x8*>(qbase + mi * 16 * 128 + kk * 32 + quad * 8);

  const f16* kbase = Kt + (size_t)(b * 8 + kv) * 2048 * 128;
  const f16* vbase = Vt + (size_t)(b * 8 + kv) * 128 * 2048;

  float m_[2][4], l_[2][4];
#pragma unroll
  for (int mi = 0; mi < 2; ++mi)
#pragma unroll
    for (int r = 0; r < 4; ++r) { m_[mi][r] = -1e30f; l_[mi][r] = 0.f; }
  f32x4 oacc[2][8] = {};

  const int nIter = 2 * t + 2;
  for (int it = 0; it < nIter; ++it) {
    const int kt0 = it * 64;
    // ---- async-stage K (64x128) + V^T (128x64), XOR-swizzled deposit.
    // K chunk c (16B): row=c>>4, stored group g'=c&15 holds global group
    // (g'&8)|((g'&7)^(row&7)). V chunk c: row=c>>3, g'=c&7 holds g'^(row&7).
#pragma unroll
    for (int i = 0; i < 4; ++i) {
      const int c = (wv * 4 + i) * 64 + lane;
      const int kr = c >> 4, kg = c & 15;
      const int kgs = (kg & 8) | ((kg & 7) ^ (kr & 7));
      ASYNC_LD16(kbase + (size_t)(kt0 + kr) * 128 + kgs * 8,
                 (char*)Ks + (wv * 4 + i) * 1024);
      const int vr = c >> 3, vg = c & 7;
      const int vgs = vg ^ (vr & 7);
      ASYNC_LD16(vbase + (size_t)vr * 2048 + kt0 + vgs * 8,
                 (char*)Vs + (wv * 4 + i) * 1024);
    }
    __syncthreads();  // drains vmcnt: tile present, prior reads done
    if (kt0 <= qw0 + 31) {  // skip fully-masked tail tiles for lower waves
      f32x4 sacc[2][4] = {};
#pragma unroll
      for (int kk = 0; kk < 4; ++kk)
#pragma unroll
        for (int ni = 0; ni < 4; ++ni) {
          const int gk = kk * 4 + quad;
          const int gks = (gk & 8) | ((gk & 7) ^ (cl & 7));
          f16x8 bk =
              *reinterpret_cast<const f16x8*>(Ks + (ni * 16 + cl) * 128 + gks * 8);
#pragma unroll
          for (int mi = 0; mi < 2; ++mi)
            sacc[mi][ni] =
                __builtin_amdgcn_mfma_f32_16x16x32_f16(aq[mi][kk], bk, sacc[mi][ni], 0, 0, 0);
        }
      if (kt0 + 63 > qw0) {  // diagonal region for this wave
#pragma unroll
        for (int mi = 0; mi < 2; ++mi) {
          const int qr = qw0 + mi * 16 + quad * 4;
#pragma unroll
          for (int ni = 0; ni < 4; ++ni) {
            const int kg2 = kt0 + ni * 16 + cl;
#pragma unroll
            for (int r = 0; r < 4; ++r)
              if (kg2 > qr + r) sacc[mi][ni][r] = -1e30f;
          }
        }
      }
      float alv[2][4];
#pragma unroll
      for (int mi = 0; mi < 2; ++mi)
#pragma unroll
        for (int r = 0; r < 4; ++r) {
          float mx = fmaxf(fmaxf(sacc[mi][0][r], sacc[mi][1][r]),
                           fmaxf(sacc[mi][2][r], sacc[mi][3][r]));
          mx = dpp_max16(mx);
          const float nm = fmaxf(m_[mi][r], mx);
          const float al = __builtin_amdgcn_exp2f(m_[mi][r] - nm);
          m_[mi][r] = nm;
          float ps = 0.f;
#pragma unroll
          for (int ni = 0; ni < 4; ++ni) {
            const float p = __builtin_amdgcn_exp2f(sacc[mi][ni][r] - nm);
            sacc[mi][ni][r] = p;
            ps += p;
          }
          l_[mi][r] = l_[mi][r] * al + ps;
          alv[mi][r] = al;
        }
#pragma unroll
      for (int mi = 0; mi < 2; ++mi)
#pragma unroll
        for (int ni = 0; ni < 4; ++ni)
#pragma unroll
          for (int r = 0; r < 4; ++r)
            Ps[wv][mi * 16 + quad * 4 + r][ni * 16 + cl] = (f16)sacc[mi][ni][r];
#pragma unroll
      for (int mi = 0; mi < 2; ++mi)
#pragma unroll
        for (int dg = 0; dg < 8; ++dg)
#pragma unroll
          for (int r = 0; r < 4; ++r) oacc[mi][dg][r] *= alv[mi][r];
      asm volatile("s_waitcnt lgkmcnt(0)" ::: "memory");  // Ps is per-wave
      f16x8 ap[2][2];
#pragma unroll
      for (int mi = 0; mi < 2; ++mi)
#pragma unroll
        for (int kh = 0; kh < 2; ++kh)
          ap[mi][kh] =
              *reinterpret_cast<const f16x8*>(&Ps[wv][mi * 16 + cl][kh * 32 + quad * 8]);
#pragma unroll
      for (int kh = 0; kh < 2; ++kh)
#pragma unroll
        for (int dg = 0; dg < 8; ++dg) {
          const int gv = kh * 4 + quad;
          const int gvs = gv ^ (cl & 7);
          f16x8 bv =
              *reinterpret_cast<const f16x8*>(Vs + (dg * 16 + cl) * 64 + gvs * 8);
#pragma unroll
          for (int mi = 0; mi < 2; ++mi)
            oacc[mi][dg] =
                __builtin_amdgcn_mfma_f32_16x16x32_f16(ap[mi][kh], bv, oacc[mi][dg], 0, 0, 0);
        }
    }
    __syncthreads();  // protect Ks/Vs before next stage
  }
#pragma unroll
  for (int mi = 0; mi < 2; ++mi)
#pragma unroll
    for (int r = 0; r < 4; ++r) {
      const float inv = 1.0f / dpp_sum16(l_[mi][r]);
      const int qg = qw0 + mi * 16 + quad * 4 + r;
#pragma unroll
      for (int dg = 0; dg < 8; ++dg)
        Ot[(size_t)(b * 2048 + qg) * 2048 + h * 128 + dg * 16 + cl] =
            (f16)(oacc[mi][dg][r] * inv);
    }
}

// ---------------------------------------------------------------------- launch
extern "C" void kernel_launch(void* const* d_in, const int* in_sizes, int n_in,
                              void* d_out, int out_size, void* d_ws, size_t ws_size,
                              hipStream_t stream) {
  (void)in_sizes; (void)n_in; (void)out_size; (void)ws_size;
  const float* hidden = (const float*)d_in[0];
  const float* cosT = (const float*)d_in[1];
  const float* sinT = (const float*)d_in[2];
  // d_in[3] = attention_mask: exactly causal triu * -1e9 -> computed analytically
  const float* Wq = (const float*)d_in[4];
  const float* Wk = (const float*)d_in[5];
  const float* Wv = (const float*)d_in[6];
  const float* Wo = (const float*)d_in[7];
  const float* qnw = (const float*)d_in[8];
  const float* knw = (const float*)d_in[9];
  float* out = (float*)d_out;

  char* ws = (char*)d_ws;
  size_t off = 0;
  auto alloc = [&](size_t bytes) {
    char* p = ws + off;
    off += (bytes + 255) & ~(size_t)255;
    return p;
  };
  f16* hb = (f16*)alloc(4096ull * 1024 * 2);
  f16* wqkv = (f16*)alloc(4096ull * 1024 * 2);   // [Wq;Wk;Wv] rows
  f16* wob = (f16*)alloc(1024ull * 2048 * 2);
  f16* qkvh = (f16*)alloc(4096ull * 4096 * 2);
  f16* qt = (f16*)alloc(32ull * 2048 * 128 * 2);
  f16* kt = (f16*)alloc(16ull * 2048 * 128 * 2);
  f16* vt = (f16*)alloc(16ull * 2048 * 128 * 2);
  f16* ot = (f16*)alloc(4096ull * 2048 * 2);

  cast_all<<<10240, 256, 0, stream>>>(hidden, Wq, Wk, Wv, Wo, hb, wqkv, wob);

  gemm_bt_h<<<dim3(32, 32), 256, 0, stream>>>(hb, wqkv, qkvh, 4096, 4096, 1024);

  rope_norm<<<24576, 256, 0, stream>>>(qkvh, cosT, sinT, qnw, knw, qt, kt);
  v_transpose<<<dim3(32, 16), 256, 0, stream>>>(qkvh, vt);

  attn<<<512, 256, 0, stream>>>(qt, kt, vt, ot);

  gemm_bt64<<<dim3(8, 64), 256, 0, stream>>>(ot, wob, out, 4096, 1024, 2048);
}

// Round 8
// 303.992 us; speedup vs baseline: 1.2667x; 1.1072x over previous
//
#include <hip/hip_runtime.h>
#include <hip/hip_fp16.h>

// Qwen3 attention block: B=2 S=2048 HID=1024 NH=16 NKV=8 HD=128, causal.
// R8: attn = R5 grid skeleton (1024 blocks x 128 thr, 2 waves, K-tile 64,
//     longest-first) + async XOR-swizzled K/V staging (R7-verified) +
//     transposed-score S^T = K*Q^T: per-lane softmax (q=cl), packed b64
//     Ps writes, PV transposed on 16x16x32 (A=V^T, B=P^T), b64 O stores.

typedef _Float16 f16;
typedef __attribute__((ext_vector_type(8))) _Float16 f16x8;
typedef __attribute__((ext_vector_type(4))) _Float16 f16x4;
typedef __attribute__((ext_vector_type(4))) float f32x4;

__constant__ const float kEps = 1e-6f;
// 1/sqrt(128) * log2(e): Q pre-scaled so attn softmax runs in exp2 domain
__constant__ const float kScaleL2 = 0.1275179120685481f;

// async global->LDS, 16B/lane; lds ptr must be wave-uniform (HW adds lane*16)
#define ASYNC_LD16(gp, lp)                                              \
  __builtin_amdgcn_global_load_lds(                                     \
      (const __attribute__((address_space(1))) void*)(gp),              \
      (__attribute__((address_space(3))) void*)(uint32_t)(uintptr_t)(lp), 16, 0, 0)

// ------------------------------------------------ fused cast f32->f16 (all 5)
__global__ __launch_bounds__(256) void cast_all(
    const float* __restrict__ h, const float* __restrict__ wq,
    const float* __restrict__ wk, const float* __restrict__ wv,
    const float* __restrict__ wo, f16* __restrict__ hb,
    f16* __restrict__ wqkv, f16* __restrict__ wob) {
  const int idx = blockIdx.x * 256 + threadIdx.x;
  const float* src;
  f16* dst;
  int base;
  if (idx < 1048576) { src = h;  dst = hb;                  base = 0; }
  else if (idx < 1572864) { src = wq; dst = wqkv;               base = 1048576; }
  else if (idx < 1835008) { src = wk; dst = wqkv + 2048 * 1024; base = 1572864; }
  else if (idx < 2097152) { src = wv; dst = wqkv + 3072 * 1024; base = 1835008; }
  else { src = wo; dst = wob; base = 2097152; }
  const int i = (idx - base) * 4;
  f32x4 v = *reinterpret_cast<const f32x4*>(src + i);
  f16x4 o;
  o.x = (f16)v.x; o.y = (f16)v.y; o.z = (f16)v.z; o.w = (f16)v.w;
  *reinterpret_cast<f16x4*>(dst + i) = o;
}

// --------------------------- C[M,N] = A[M,K]*B[N,K]^T, f16 out (QKV proj)
__global__ __launch_bounds__(256) void gemm_bt_h(const f16* __restrict__ A,
                                                 const f16* __restrict__ Bm,
                                                 f16* __restrict__ C,
                                                 int M, int N, int K) {
  __shared__ __align__(16) f16 As[128][64];
  __shared__ __align__(16) f16 Bs[128][64];
  const int tid = threadIdx.x;
  const int lane = tid & 63;
  const int wave = tid >> 6;
  const int cl = lane & 15;
  const int quad = lane >> 4;
  const int wm = (wave >> 1) * 64;
  const int wn = (wave & 1) * 64;
  const int tm = blockIdx.y * 128;
  const int tn = blockIdx.x * 128;
  const int r0 = tid >> 3;
  const int csw = ((tid & 7) ^ (r0 & 7)) * 8;

  const f16* Ab = A + (size_t)(tm + r0) * K + csw;
  const f16* Bb = Bm + (size_t)(tn + r0) * K + csw;
  char* Al = (char*)As + wave * 1024;
  char* Bl = (char*)Bs + wave * 1024;

  f32x4 acc[4][4] = {};

  for (int k0 = 0; k0 < K; k0 += 64) {
#pragma unroll
    for (int c = 0; c < 4; ++c) {
      ASYNC_LD16(Ab + (size_t)(c * 32) * K + k0, Al + c * 4096);
      ASYNC_LD16(Bb + (size_t)(c * 32) * K + k0, Bl + c * 4096);
    }
    __syncthreads();
#pragma unroll
    for (int kk = 0; kk < 2; ++kk) {
      f16x8 af[4], bf[4];
#pragma unroll
      for (int mi = 0; mi < 4; ++mi)
        af[mi] = *reinterpret_cast<const f16x8*>(
            &As[wm + mi * 16 + cl][((kk * 4 + quad) ^ (cl & 7)) * 8]);
#pragma unroll
      for (int ni = 0; ni < 4; ++ni)
        bf[ni] = *reinterpret_cast<const f16x8*>(
            &Bs[wn + ni * 16 + cl][((kk * 4 + quad) ^ (cl & 7)) * 8]);
#pragma unroll
      for (int mi = 0; mi < 4; ++mi)
#pragma unroll
        for (int ni = 0; ni < 4; ++ni)
          acc[mi][ni] =
              __builtin_amdgcn_mfma_f32_16x16x32_f16(af[mi], bf[ni], acc[mi][ni], 0, 0, 0);
    }
    __syncthreads();
  }
#pragma unroll
  for (int mi = 0; mi < 4; ++mi)
#pragma unroll
    for (int ni = 0; ni < 4; ++ni)
#pragma unroll
      for (int r = 0; r < 4; ++r)
        C[(size_t)(tm + wm + mi * 16 + quad * 4 + r) * N + tn + wn + ni * 16 + cl] =
            (f16)acc[mi][ni][r];
}

// --------------------------- C[M,N] = A[M,K]*B[N,K]^T, f32 out (out proj)
__global__ __launch_bounds__(256) void gemm_bt64(const f16* __restrict__ A,
                                                 const f16* __restrict__ Bm,
                                                 float* __restrict__ C,
                                                 int M, int N, int K) {
  __shared__ __align__(16) f16 As[64][64];
  __shared__ __align__(16) f16 Bs[128][64];
  const int tid = threadIdx.x;
  const int lane = tid & 63;
  const int wave = tid >> 6;
  const int cl = lane & 15;
  const int quad = lane >> 4;
  const int wm = (wave >> 1) * 32;
  const int wn = (wave & 1) * 64;
  const int tm = blockIdx.y * 64;
  const int tn = blockIdx.x * 128;
  const int r0 = tid >> 3;
  const int csw = ((tid & 7) ^ (r0 & 7)) * 8;

  const f16* Ab = A + (size_t)(tm + r0) * K + csw;
  const f16* Bb = Bm + (size_t)(tn + r0) * K + csw;
  char* Al = (char*)As + wave * 1024;
  char* Bl = (char*)Bs + wave * 1024;

  f32x4 acc[2][4] = {};

  for (int k0 = 0; k0 < K; k0 += 64) {
#pragma unroll
    for (int c = 0; c < 2; ++c)
      ASYNC_LD16(Ab + (size_t)(c * 32) * K + k0, Al + c * 4096);
#pragma unroll
    for (int c = 0; c < 4; ++c)
      ASYNC_LD16(Bb + (size_t)(c * 32) * K + k0, Bl + c * 4096);
    __syncthreads();
#pragma unroll
    for (int kk = 0; kk < 2; ++kk) {
      f16x8 af[2], bf[4];
#pragma unroll
      for (int mi = 0; mi < 2; ++mi)
        af[mi] = *reinterpret_cast<const f16x8*>(
            &As[wm + mi * 16 + cl][((kk * 4 + quad) ^ (cl & 7)) * 8]);
#pragma unroll
      for (int ni = 0; ni < 4; ++ni)
        bf[ni] = *reinterpret_cast<const f16x8*>(
            &Bs[wn + ni * 16 + cl][((kk * 4 + quad) ^ (cl & 7)) * 8]);
#pragma unroll
      for (int mi = 0; mi < 2; ++mi)
#pragma unroll
        for (int ni = 0; ni < 4; ++ni)
          acc[mi][ni] =
              __builtin_amdgcn_mfma_f32_16x16x32_f16(af[mi], bf[ni], acc[mi][ni], 0, 0, 0);
    }
    __syncthreads();
  }
#pragma unroll
  for (int mi = 0; mi < 2; ++mi)
#pragma unroll
    for (int ni = 0; ni < 4; ++ni)
#pragma unroll
      for (int r = 0; r < 4; ++r)
        C[(size_t)(tm + wm + mi * 16 + quad * 4 + r) * N + tn + wn + ni * 16 + cl] =
            acc[mi][ni][r];
}

// -------------------------- RMSNorm + RoPE + transpose for Q,K (wave per row)
__global__ __launch_bounds__(256) void rope_norm(
    const f16* __restrict__ qkvh,
    const float* __restrict__ cosT, const float* __restrict__ sinT,
    const float* __restrict__ qw, const float* __restrict__ kw,
    f16* __restrict__ qt, f16* __restrict__ kt) {
  const int gw = blockIdx.x * 4 + (threadIdx.x >> 6);
  const int lane = threadIdx.x & 63;
  const int head = gw % 24;
  const int bs = gw / 24;
  const bool isq = head < 16;
  const f16* src = qkvh + (size_t)bs * 4096 +
                   (isq ? head * 128 : 2048 + (head - 16) * 128);
  const float x1 = (float)src[lane];
  const float x2 = (float)src[lane + 64];
  float ss = x1 * x1 + x2 * x2;
#pragma unroll
  for (int off = 32; off >= 1; off >>= 1) ss += __shfl_xor(ss, off);
  const float rms = rsqrtf(ss * (1.0f / 128.0f) + kEps);
  const float* w = isq ? qw : kw;
  const float n1 = x1 * rms * w[lane];
  const float n2 = x2 * rms * w[lane + 64];
  const float* cb = cosT + (size_t)bs * 128;
  const float* sb = sinT + (size_t)bs * 128;
  const float o1 = n1 * cb[lane] - n2 * sb[lane];
  const float o2 = n2 * cb[lane + 64] + n1 * sb[lane + 64];
  const int b = bs >> 11;
  const int s = bs & 2047;
  f16* dst;
  float sc;
  if (isq) {
    dst = qt + ((size_t)(b * 16 + head) * 2048 + s) * 128;
    sc = kScaleL2;
  } else {
    dst = kt + ((size_t)(b * 8 + (head - 16)) * 2048 + s) * 128;
    sc = 1.0f;
  }
  dst[lane] = (f16)(o1 * sc);
  dst[lane + 64] = (f16)(o2 * sc);
}

// ------------------------------- V slice of qkvh f16 -> (B*NKV, HD, S) f16
__global__ __launch_bounds__(256) void v_transpose(const f16* __restrict__ qkvh,
                                                   f16* __restrict__ vt) {
  __shared__ __align__(16) f16 tile[64][136];
  const int bh = blockIdx.y;
  const int b = bh >> 3, h = bh & 7;
  const int s0 = blockIdx.x * 64;
  const int tid = threadIdx.x;
#pragma unroll
  for (int i = 0; i < 4; ++i) {
    int c = tid + i * 256;
    int s = c >> 4;
    int cg = c & 15;
    f16x8 v = *reinterpret_cast<const f16x8*>(
        qkvh + (size_t)(b * 2048 + s0 + s) * 4096 + 3072 + h * 128 + cg * 8);
    *reinterpret_cast<f16x8*>(&tile[s][cg * 8]) = v;
  }
  __syncthreads();
#pragma unroll
  for (int i = 0; i < 4; ++i) {
    int c = tid + i * 256;
    int d = c >> 3;
    int sB = (c & 7) * 8;
    f16x8 o;
#pragma unroll
    for (int j = 0; j < 8; ++j) o[j] = tile[sB + j][d];
    *reinterpret_cast<f16x8*>(vt + ((size_t)(b * 8 + h) * 128 + d) * 2048 + s0 + sB) = o;
  }
}

// ------------------------------------------------------- flash attention (causal)
// 1024 blocks x 128 threads (2 waves); wave owns 32 q; K-tile 64.
// S^T = K*Q^T (A=K, B=Q; identical lane maps) -> P^T at (s=quad*4+r, q=cl):
// per-lane softmax state, b64 Ps writes to [q][s], PV transposed on
// 16x16x32 (A=V^T frags, B=P^T from Ps), b64 packed O stores.
// K/V async-staged via global_load_lds with XOR swizzle (R7-verified).
__global__ __launch_bounds__(128) void attn(const f16* __restrict__ Qt,
                                            const f16* __restrict__ Kt,
                                            const f16* __restrict__ Vt,
                                            f16* __restrict__ Ot) {
  __shared__ __align__(16) f16 Ks[64 * 128];   // 16 KB swizzled (s,d)
  __shared__ __align__(16) f16 Vs[128 * 64];   // 16 KB swizzled (d,s)
  __shared__ __align__(16) f16 Ps[2][32][72];  // 9 KB  [wave][q][s]

  const int bid = blockIdx.x;
  const int bh = bid & 31;
  const int t = 31 - (bid >> 5);   // longest tiles first
  const int q0 = t * 64;
  const int b = bh >> 4, h = bh & 15;
  const int kv = h >> 1;

  const int tid = threadIdx.x;
  const int lane = tid & 63, wv = tid >> 6;
  const int cl = lane & 15, quad = lane >> 4;
  const int qw0 = q0 + wv * 32;               // wave's first q-row

  // Q frags: lane cl = q-row qw0+mi*16+cl, k = d = kk*32+quad*8+j
  const f16* qbase = Qt + ((size_t)(b * 16 + h) * 2048 + qw0 + cl) * 128;
  f16x8 aq[2][4];
#pragma unroll
  for (int mi = 0; mi < 2; ++mi)
#pragma unroll
    for (int kk = 0; kk < 4; ++kk)
      aq[mi][kk] =
          *reinterpret_cast<const f16x8*>(qbase + mi * 16 * 128 + kk * 32 + quad * 8);

  const f16* kbase = Kt + (size_t)(b * 8 + kv) * 2048 * 128;
  const f16* vbase = Vt + (size_t)(b * 8 + kv) * 128 * 2048;

  float m_[2] = {-1e30f, -1e30f}, l_[2] = {0.f, 0.f};  // per-lane q state
  f32x4 oacc[2][8] = {};                                // D[m=d][n=q=cl]

  for (int kt0 = 0; kt0 <= q0; kt0 += 64) {
    // ---- async-stage K (64x128) + V^T (128x64), XOR-swizzled deposit
#pragma unroll
    for (int i = 0; i < 8; ++i) {
      const int c = (wv * 8 + i) * 64 + lane;
      const int kr = c >> 4, kg = c & 15;
      const int kgs = (kg & 8) | ((kg & 7) ^ (kr & 7));
      ASYNC_LD16(kbase + (size_t)(kt0 + kr) * 128 + kgs * 8,
                 (char*)Ks + (wv * 8 + i) * 1024);
      const int vr = c >> 3, vg = c & 7;
      const int vgs = vg ^ (vr & 7);
      ASYNC_LD16(vbase + (size_t)vr * 2048 + kt0 + vgs * 8,
                 (char*)Vs + (wv * 8 + i) * 1024);
    }
    __syncthreads();  // drains vmcnt: tile present, prior reads done
    // ---- S^T = K*Q^T: A = K-frag (m=s), B = Q-frag (n=q)
    f32x4 sacc[2][4] = {};
#pragma unroll
    for (int kk = 0; kk < 4; ++kk)
#pragma unroll
      for (int ni = 0; ni < 4; ++ni) {
        const int gk = kk * 4 + quad;
        const int gks = (gk & 8) | ((gk & 7) ^ (cl & 7));
        f16x8 ak =
            *reinterpret_cast<const f16x8*>(Ks + (ni * 16 + cl) * 128 + gks * 8);
#pragma unroll
        for (int mi = 0; mi < 2; ++mi)
          sacc[mi][ni] =
              __builtin_amdgcn_mfma_f32_16x16x32_f16(ak, aq[mi][kk], sacc[mi][ni], 0, 0, 0);
      }
    // ---- causal mask (diagonal tile): s = kt0+ni*16+quad*4+r, q = qw0+mi*16+cl
    if (kt0 == q0) {
#pragma unroll
      for (int mi = 0; mi < 2; ++mi) {
        const int qg = qw0 + mi * 16 + cl;
#pragma unroll
        for (int ni = 0; ni < 4; ++ni) {
          const int sg = kt0 + ni * 16 + quad * 4;
#pragma unroll
          for (int r = 0; r < 4; ++r)
            if (sg + r > qg) sacc[mi][ni][r] = -1e30f;
        }
      }
    }
    // ---- softmax (exp2 domain), per-lane q; l stays quad-partial
    float al[2];
#pragma unroll
    for (int mi = 0; mi < 2; ++mi) {
      float m0 = sacc[mi][0][0];
#pragma unroll
      for (int ni = 0; ni < 4; ++ni)
#pragma unroll
        for (int r = 0; r < 4; ++r) m0 = fmaxf(m0, sacc[mi][ni][r]);
      m0 = fmaxf(m0, __shfl_xor(m0, 16));
      m0 = fmaxf(m0, __shfl_xor(m0, 32));
      const float nm = fmaxf(m_[mi], m0);
      al[mi] = __builtin_amdgcn_exp2f(m_[mi] - nm);
      m_[mi] = nm;
      float ps = 0.f;
#pragma unroll
      for (int ni = 0; ni < 4; ++ni)
#pragma unroll
        for (int r = 0; r < 4; ++r) {
          const float p = __builtin_amdgcn_exp2f(sacc[mi][ni][r] - nm);
          sacc[mi][ni][r] = p;
          ps += p;
        }
      l_[mi] = l_[mi] * al[mi] + ps;
    }
    // ---- P^T to Ps[q][s]: packed b64 (4 consecutive s per lane)
#pragma unroll
    for (int mi = 0; mi < 2; ++mi)
#pragma unroll
      for (int ni = 0; ni < 4; ++ni) {
        f16x4 pk;
#pragma unroll
        for (int r = 0; r < 4; ++r) pk[r] = (f16)sacc[mi][ni][r];
        *reinterpret_cast<f16x4*>(&Ps[wv][mi * 16 + cl][ni * 16 + quad * 4]) = pk;
      }
    // ---- rescale O (per-lane scalar al)
#pragma unroll
    for (int mi = 0; mi < 2; ++mi)
#pragma unroll
      for (int dg = 0; dg < 8; ++dg) oacc[mi][dg] *= al[mi];
    asm volatile("s_waitcnt lgkmcnt(0)" ::: "memory");  // Ps is per-wave
    // ---- PV^T: D[m=d][n=q] += V^T * P^T; A=V-frag, B=P^T-frag
    f16x8 bp[2][2];
#pragma unroll
    for (int mi = 0; mi < 2; ++mi)
#pragma unroll
      for (int kh = 0; kh < 2; ++kh)
        bp[mi][kh] =
            *reinterpret_cast<const f16x8*>(&Ps[wv][mi * 16 + cl][kh * 32 + quad * 8]);
#pragma unroll
    for (int kh = 0; kh < 2; ++kh)
#pragma unroll
      for (int dg = 0; dg < 8; ++dg) {
        const int gv = kh * 4 + quad;
        const int gvs = gv ^ (cl & 7);
        f16x8 av =
            *reinterpret_cast<const f16x8*>(Vs + (dg * 16 + cl) * 64 + gvs * 8);
#pragma unroll
        for (int mi = 0; mi < 2; ++mi)
          oacc[mi][dg] =
              __builtin_amdgcn_mfma_f32_16x16x32_f16(av, bp[mi][kh], oacc[mi][dg], 0, 0, 0);
      }
    __syncthreads();  // protect Ks/Vs before next stage
  }
  // ---- finalize: l summed across quads; O: lane q=cl, d=dg*16+quad*4+r
#pragma unroll
  for (int mi = 0; mi < 2; ++mi) {
    float l = l_[mi];
    l += __shfl_xor(l, 16);
    l += __shfl_xor(l, 32);
    const float inv = 1.0f / l;
    const size_t qg = qw0 + mi * 16 + cl;
#pragma unroll
    for (int dg = 0; dg < 8; ++dg) {
      f16x4 o;
#pragma unroll
      for (int r = 0; r < 4; ++r) o[r] = (f16)(oacc[mi][dg][r] * inv);
      *reinterpret_cast<f16x4*>(Ot + ((size_t)b * 2048 + qg) * 2048 + h * 128 +
                                dg * 16 + quad * 4) = o;
    }
  }
}

// ---------------------------------------------------------------------- launch
extern "C" void kernel_launch(void* const* d_in, const int* in_sizes, int n_in,
                              void* d_out, int out_size, void* d_ws, size_t ws_size,
                              hipStream_t stream) {
  (void)in_sizes; (void)n_in; (void)out_size; (void)ws_size;
  const float* hidden = (const float*)d_in[0];
  const float* cosT = (const float*)d_in[1];
  const float* sinT = (const float*)d_in[2];
  // d_in[3] = attention_mask: exactly causal triu * -1e9 -> computed analytically
  const float* Wq = (const float*)d_in[4];
  const float* Wk = (const float*)d_in[5];
  const float* Wv = (const float*)d_in[6];
  const float* Wo = (const float*)d_in[7];
  const float* qnw = (const float*)d_in[8];
  const float* knw = (const float*)d_in[9];
  float* out = (float*)d_out;

  char* ws = (char*)d_ws;
  size_t off = 0;
  auto alloc = [&](size_t bytes) {
    char* p = ws + off;
    off += (bytes + 255) & ~(size_t)255;
    return p;
  };
  f16* hb = (f16*)alloc(4096ull * 1024 * 2);
  f16* wqkv = (f16*)alloc(4096ull * 1024 * 2);   // [Wq;Wk;Wv] rows
  f16* wob = (f16*)alloc(1024ull * 2048 * 2);
  f16* qkvh = (f16*)alloc(4096ull * 4096 * 2);
  f16* qt = (f16*)alloc(32ull * 2048 * 128 * 2);
  f16* kt = (f16*)alloc(16ull * 2048 * 128 * 2);
  f16* vt = (f16*)alloc(16ull * 2048 * 128 * 2);
  f16* ot = (f16*)alloc(4096ull * 2048 * 2);

  cast_all<<<10240, 256, 0, stream>>>(hidden, Wq, Wk, Wv, Wo, hb, wqkv, wob);

  gemm_bt_h<<<dim3(32, 32), 256, 0, stream>>>(hb, wqkv, qkvh, 4096, 4096, 1024);

  rope_norm<<<24576, 256, 0, stream>>>(qkvh, cosT, sinT, qnw, knw, qt, kt);
  v_transpose<<<dim3(32, 16), 256, 0, stream>>>(qkvh, vt);

  attn<<<1024, 128, 0, stream>>>(qt, kt, vt, ot);

  gemm_bt64<<<dim3(8, 64), 256, 0, stream>>>(ot, wob, out, 4096, 1024, 2048);
}